// Round 4
// baseline (75.407 us; speedup 1.0000x reference)
//
#include <hip/hip_runtime.h>

// ForgetMult (QRNN): xi (8,128,64,32,32) f32.
//   f = sigmoid(xi[:, :64]); x = xi[:, 64:]
//   h_t = f_t * x_t + (1 - f_t) * h_{t-1}  (scan over axis 2, T=64)
// Output (8,64,64,32,32) f32.
//
// R4: scalar f32 per thread -> 524288 threads -> 2048 blocks ->
// 32 waves/CU (hardware max occupancy). Wave load = 256 B contiguous
// (still fully coalesced). NT loads/stores, approx-rcp sigmoid, unroll 8.
// VALU demand at BW-limit elem rate ~16% of capacity -> still memory-bound.

#define T_STEPS 64
#define SP 1024   // floats per (b,c,t) spatial slice (32*32)

__global__ __launch_bounds__(256)
void forgetmult_kernel(const float* __restrict__ xi, float* __restrict__ out) {
    const int blk = blockIdx.x;           // ((b*64)+c)*4 + quarter
    const int b   = blk >> 8;
    const int rem = blk & 255;
    const int c   = rem >> 2;
    const int q   = rem & 3;
    const int s   = q * 256 + threadIdx.x;   // 0..1023 float-index in slice

    const size_t fbase = ((size_t)(b * 128 + c) * T_STEPS) * SP + s;
    const size_t xbase = ((size_t)(b * 128 + 64 + c) * T_STEPS) * SP + s;
    const size_t obase = ((size_t)(b * 64 + c) * T_STEPS) * SP + s;

    float h = 0.f;

    #pragma unroll 8
    for (int t = 0; t < T_STEPS; ++t) {
        const float fr = __builtin_nontemporal_load(&xi[fbase + (size_t)t * SP]);
        const float xr = __builtin_nontemporal_load(&xi[xbase + (size_t)t * SP]);

        // sigmoid via fast exp + approx rcp (absmax threshold 9.2e-2 >> rcp err)
        const float f = __builtin_amdgcn_rcpf(1.0f + __expf(-fr));

        // h = f*x + (1-f)*h  ==  h + f*(x - h)
        h = fmaf(f, xr - h, h);

        __builtin_nontemporal_store(h, &out[obase + (size_t)t * SP]);
    }
}

extern "C" void kernel_launch(void* const* d_in, const int* in_sizes, int n_in,
                              void* d_out, int out_size, void* d_ws, size_t ws_size,
                              hipStream_t stream) {
    const float* xi = (const float*)d_in[0];
    float* out = (float*)d_out;
    // 8 b * 64 c * 4 quarters = 2048 blocks, 256 threads each
    forgetmult_kernel<<<dim3(2048), dim3(256), 0, stream>>>(xi, out);
}